// Round 1
// baseline (251.864 us; speedup 1.0000x reference)
//
#include <hip/hip_runtime.h>
#include <math.h>

#define NB 16384
#define NG 10000
#define NCHUNK 16
#define CS 625           // NG / NCHUNK exactly
#define Y4STRIDE 12      // 9 SH values + 3 raw grid-vec components per g

// ---------------- Kernel 1: Y4 (l=4 real SH) + raw grid vec, packed ----------------
__global__ __launch_bounds__(256) void k_y4(const float* __restrict__ gv,
                                            float* __restrict__ y4p) {
    int g = blockIdx.x * 256 + threadIdx.x;
    if (g >= NG) return;
    float x = gv[3 * g + 0], y = gv[3 * g + 1], z = gv[3 * g + 2];
    float n = sqrtf(x * x + y * y + z * z);
    float dn = fmaxf(n, 1e-12f);
    float vx = x / dn, vy = y / dn, vz = z / dn;
    float x2 = vx * vx, y2 = vy * vy, z2 = vz * vz;
    const float c_m4 = (float)(0.75 * sqrt(35.0 / M_PI));
    const float c_m3 = (float)(0.75 * sqrt(35.0 / (2.0 * M_PI)));
    const float c_m2 = (float)(0.75 * sqrt(5.0 / M_PI));
    const float c_m1 = (float)(0.75 * sqrt(5.0 / (2.0 * M_PI)));
    const float c_0  = (float)((3.0 / 16.0) * sqrt(1.0 / M_PI));
    const float c_p2 = (float)((3.0 / 8.0) * sqrt(5.0 / M_PI));
    const float c_p4 = (float)((3.0 / 16.0) * sqrt(35.0 / M_PI));
    float* o = y4p + (size_t)g * Y4STRIDE;
    o[0] = c_m4 * vx * vy * (x2 - y2);
    o[1] = c_m3 * vy * vz * (3.0f * x2 - y2);
    o[2] = c_m2 * vx * vy * (7.0f * z2 - 1.0f);
    o[3] = c_m1 * vy * vz * (7.0f * z2 - 3.0f);
    o[4] = c_0  * (35.0f * z2 * z2 - 30.0f * z2 + 3.0f);
    o[5] = c_m1 * vx * vz * (7.0f * z2 - 3.0f);
    o[6] = c_p2 * (x2 - y2) * (7.0f * z2 - 1.0f);
    o[7] = c_m3 * vx * vz * (x2 - y2);
    o[8] = c_p4 * (x2 * x2 - 6.0f * x2 * y2 + y2 * y2);
    o[9] = x; o[10] = y; o[11] = z;   // raw (unnormalized) grid vec, as the reference uses
}

// ---------------- Kernel 2: pass-1 partial argmax of signal over a g-chunk ----------------
__global__ __launch_bounds__(256) void k_pass1(const float* __restrict__ f4,
                                               const float* __restrict__ y4p,
                                               float* __restrict__ pval,
                                               int* __restrict__ pidx) {
    int b = blockIdx.x * 256 + threadIdx.x;
    int c = blockIdx.y;
    const float* a = f4 + (size_t)b * 9;
    float a0 = a[0], a1 = a[1], a2 = a[2], a3 = a[3], a4 = a[4],
          a5 = a[5], a6 = a[6], a7 = a[7], a8 = a[8];
    float best = -INFINITY;
    int bi = 0;
    int g0 = c * CS;
    const float* yr = y4p + (size_t)g0 * Y4STRIDE;
#pragma unroll 5
    for (int g = g0; g < g0 + CS; ++g, yr += Y4STRIDE) {
        float s = a0 * yr[0];
        s = fmaf(a1, yr[1], s);
        s = fmaf(a2, yr[2], s);
        s = fmaf(a3, yr[3], s);
        s = fmaf(a4, yr[4], s);
        s = fmaf(a5, yr[5], s);
        s = fmaf(a6, yr[6], s);
        s = fmaf(a7, yr[7], s);
        s = fmaf(a8, yr[8], s);
        if (s > best) { best = s; bi = g; }
    }
    pval[c * NB + b] = best;
    pidx[c * NB + b] = bi;
}

// ---------------- Kernel 3: pass-2 masked partial argmax over a g-chunk ----------------
__global__ __launch_bounds__(256) void k_pass2(const float* __restrict__ f4,
                                               const float* __restrict__ y4p,
                                               const float* __restrict__ p1val,
                                               const int* __restrict__ p1idx,
                                               float* __restrict__ p2val,
                                               int* __restrict__ p2idx) {
    int b = blockIdx.x * 256 + threadIdx.x;
    int c = blockIdx.y;
    // combine pass-1 partials (ascending chunk order, strict > == first-max)
    float bv = -INFINITY;
    int zi = 0;
#pragma unroll
    for (int cc = 0; cc < NCHUNK; ++cc) {
        float v = p1val[cc * NB + b];
        if (v > bv) { bv = v; zi = p1idx[cc * NB + b]; }
    }
    float z0 = y4p[(size_t)zi * Y4STRIDE + 9];
    float z1 = y4p[(size_t)zi * Y4STRIDE + 10];
    float z2 = y4p[(size_t)zi * Y4STRIDE + 11];
    const float* a = f4 + (size_t)b * 9;
    float a0 = a[0], a1 = a[1], a2 = a[2], a3 = a[3], a4 = a[4],
          a5 = a[5], a6 = a[6], a7 = a[7], a8 = a[8];
    float best = -INFINITY;
    int bi = 0;
    int g0 = c * CS;
    const float* yr = y4p + (size_t)g0 * Y4STRIDE;
#pragma unroll 5
    for (int g = g0; g < g0 + CS; ++g, yr += Y4STRIDE) {
        float d = z0 * yr[9];
        d = fmaf(z1, yr[10], d);
        d = fmaf(z2, yr[11], d);
        float s = a0 * yr[0];
        s = fmaf(a1, yr[1], s);
        s = fmaf(a2, yr[2], s);
        s = fmaf(a3, yr[3], s);
        s = fmaf(a4, yr[4], s);
        s = fmaf(a5, yr[5], s);
        s = fmaf(a6, yr[6], s);
        s = fmaf(a7, yr[7], s);
        s = fmaf(a8, yr[8], s);
        bool ok = (fabsf(d) < 0.2f) & (s > best);
        if (ok) { best = s; bi = g; }
    }
    p2val[c * NB + b] = best;
    p2idx[c * NB + b] = bi;
}

// ---------------- Kernel 4: finalize — frame, quaternion, boundary map ----------------
__global__ __launch_bounds__(256) void k_final(const float* __restrict__ f0,
                                               const float* __restrict__ y4p,
                                               const float* __restrict__ p1val,
                                               const int* __restrict__ p1idx,
                                               const float* __restrict__ p2val,
                                               const int* __restrict__ p2idx,
                                               float* __restrict__ out) {
    int b = blockIdx.x * 256 + threadIdx.x;
    float bv = -INFINITY; int zi = 0;
#pragma unroll
    for (int cc = 0; cc < NCHUNK; ++cc) {
        float v = p1val[cc * NB + b];
        if (v > bv) { bv = v; zi = p1idx[cc * NB + b]; }
    }
    float bx = -INFINITY; int xi = 0;
#pragma unroll
    for (int cc = 0; cc < NCHUNK; ++cc) {
        float v = p2val[cc * NB + b];
        if (v > bx) { bx = v; xi = p2idx[cc * NB + b]; }
    }
    float zr0 = y4p[(size_t)zi * Y4STRIDE + 9];
    float zr1 = y4p[(size_t)zi * Y4STRIDE + 10];
    float zr2 = y4p[(size_t)zi * Y4STRIDE + 11];
    float xr0 = y4p[(size_t)xi * Y4STRIDE + 9];
    float xr1 = y4p[(size_t)xi * Y4STRIDE + 10];
    float xr2 = y4p[(size_t)xi * Y4STRIDE + 11];
    // z = normalize(z_raw)
    float zn = sqrtf(zr0 * zr0 + zr1 * zr1 + zr2 * zr2);
    float zd = fmaxf(zn, 1e-12f);
    float z0 = zr0 / zd, z1 = zr1 / zd, z2 = zr2 / zd;
    // x = normalize(x_raw - (x_raw . z) z)
    float pr = xr0 * z0 + xr1 * z1 + xr2 * z2;
    float ux = xr0 - pr * z0, uy = xr1 - pr * z1, uz = xr2 - pr * z2;
    float xn = sqrtf(ux * ux + uy * uy + uz * uz);
    float xd = fmaxf(xn, 1e-12f);
    float x0 = ux / xd, x1 = uy / xd, x2 = uz / xd;
    // y = cross(z, x)
    float y0 = z1 * x2 - z2 * x1;
    float y1 = z2 * x0 - z0 * x2;
    float y2 = z0 * x1 - z1 * x0;
    // R columns = [x, y, z]
    float m00 = x0, m01 = y0, m02 = z0;
    float m10 = x1, m11 = y1, m12 = z1;
    float m20 = x2, m21 = y2, m22 = z2;
    float q0 = sqrtf(fmaxf(1.0f + m00 + m11 + m22, 0.0f));
    float q1 = sqrtf(fmaxf(1.0f + m00 - m11 - m22, 0.0f));
    float q2 = sqrtf(fmaxf(1.0f - m00 + m11 - m22, 0.0f));
    float q3 = sqrtf(fmaxf(1.0f - m00 - m11 + m22, 0.0f));
    int bq = 0; float qb = q0;
    if (q1 > qb) { qb = q1; bq = 1; }
    if (q2 > qb) { qb = q2; bq = 2; }
    if (q3 > qb) { qb = q3; bq = 3; }
    float dd = 2.0f * fmaxf(qb, 0.1f);
    float w, qx, qy, qz;
    if (bq == 0)      { w = q0 * q0;  qx = m21 - m12; qy = m02 - m20; qz = m10 - m01; }
    else if (bq == 1) { w = m21 - m12; qx = q1 * q1;  qy = m10 + m01; qz = m02 + m20; }
    else if (bq == 2) { w = m02 - m20; qx = m10 + m01; qy = q2 * q2;  qz = m12 + m21; }
    else              { w = m10 - m01; qx = m20 + m02; qy = m21 + m12; qz = q3 * q3; }
    out[b * 4 + 0] = w / dd;
    out[b * 4 + 1] = qx / dd;
    out[b * 4 + 2] = qy / dd;
    out[b * 4 + 3] = qz / dd;
    out[4 * NB + b] = f0[b] * (float)(180.0 / M_PI);
}

extern "C" void kernel_launch(void* const* d_in, const int* in_sizes, int n_in,
                              void* d_out, int out_size, void* d_ws, size_t ws_size,
                              hipStream_t stream) {
    const float* f0 = (const float*)d_in[0];   // [16384, 1]
    const float* f4 = (const float*)d_in[2];   // [16384, 9]
    const float* gv = (const float*)d_in[4];   // [10000, 3]
    float* out = (float*)d_out;                // q [16384,4] then boundary [16384]
    (void)in_sizes; (void)n_in; (void)out_size; (void)ws_size;

    // workspace layout (floats): y4pack | p1val | p1idx | p2val | p2idx  (~4.7 MB)
    float* Wf = (float*)d_ws;
    float* y4p  = Wf;                                   // NG*12 = 120000
    float* p1v  = Wf + (NG * Y4STRIDE);                 // NB*NCHUNK = 262144
    int*   p1i  = (int*)(Wf + NG * Y4STRIDE + NB * NCHUNK);
    float* p2v  = Wf + NG * Y4STRIDE + 2 * NB * NCHUNK;
    int*   p2i  = (int*)(Wf + NG * Y4STRIDE + 3 * NB * NCHUNK);

    k_y4<<<(NG + 255) / 256, 256, 0, stream>>>(gv, y4p);
    dim3 grid2(NB / 256, NCHUNK);
    k_pass1<<<grid2, 256, 0, stream>>>(f4, y4p, p1v, p1i);
    k_pass2<<<grid2, 256, 0, stream>>>(f4, y4p, p1v, p1i, p2v, p2i);
    k_final<<<NB / 256, 256, 0, stream>>>(f0, y4p, p1v, p1i, p2v, p2i, out);
}

// Round 2
// 209.870 us; speedup vs baseline: 1.2001x; 1.2001x over previous
//
#include <hip/hip_runtime.h>
#include <math.h>

#define NB 16384
#define NG 10000
#define NCHUNK 32
#define CS 313            // ceil(NG / NCHUNK); last chunk clamped to NG
#define Y4STRIDE 12       // [0..7]=SH pairs, [8..10]=raw vec xyz, [11]=9th SH comp

typedef float v2f __attribute__((ext_vector_type(2)));

// ---------------- Kernel 1: Y4 (l=4 real SH) + raw grid vec, packed-pair layout ----------------
__global__ __launch_bounds__(256) void k_y4(const float* __restrict__ gv,
                                            float* __restrict__ y4p) {
    int g = blockIdx.x * 256 + threadIdx.x;
    if (g >= NG) return;
    float x = gv[3 * g + 0], y = gv[3 * g + 1], z = gv[3 * g + 2];
    float n = sqrtf(x * x + y * y + z * z);
    float dn = fmaxf(n, 1e-12f);
    float vx = x / dn, vy = y / dn, vz = z / dn;
    float x2 = vx * vx, y2 = vy * vy, z2 = vz * vz;
    const float c_m4 = (float)(0.75 * sqrt(35.0 / M_PI));
    const float c_m3 = (float)(0.75 * sqrt(35.0 / (2.0 * M_PI)));
    const float c_m2 = (float)(0.75 * sqrt(5.0 / M_PI));
    const float c_m1 = (float)(0.75 * sqrt(5.0 / (2.0 * M_PI)));
    const float c_0  = (float)((3.0 / 16.0) * sqrt(1.0 / M_PI));
    const float c_p2 = (float)((3.0 / 8.0) * sqrt(5.0 / M_PI));
    const float c_p4 = (float)((3.0 / 16.0) * sqrt(35.0 / M_PI));
    float* o = y4p + (size_t)g * Y4STRIDE;
    o[0] = c_m4 * vx * vy * (x2 - y2);
    o[1] = c_m3 * vy * vz * (3.0f * x2 - y2);
    o[2] = c_m2 * vx * vy * (7.0f * z2 - 1.0f);
    o[3] = c_m1 * vy * vz * (7.0f * z2 - 3.0f);
    o[4] = c_0  * (35.0f * z2 * z2 - 30.0f * z2 + 3.0f);
    o[5] = c_m1 * vx * vz * (7.0f * z2 - 3.0f);
    o[6] = c_p2 * (x2 - y2) * (7.0f * z2 - 1.0f);
    o[7] = c_m3 * vx * vz * (x2 - y2);
    o[8] = x; o[9] = y; o[10] = z;                       // raw grid vec (pair-aligned x,y)
    o[11] = c_p4 * (x2 * x2 - 6.0f * x2 * y2 + y2 * y2); // 9th SH comp
}

// ---------------- Kernel 2: pass-1 partial argmax over a g-chunk ----------------
__global__ __launch_bounds__(256) void k_pass1(const float* __restrict__ f4,
                                               const float* __restrict__ y4p,
                                               float* __restrict__ pval,
                                               int* __restrict__ pidx) {
    int b = blockIdx.x * 256 + threadIdx.x;
    int c = blockIdx.y;
    const float* a = f4 + (size_t)b * 9;
    v2f a01 = { a[0], a[1] };
    v2f a23 = { a[2], a[3] };
    v2f a45 = { a[4], a[5] };
    v2f a67 = { a[6], a[7] };
    float a8 = a[8];
    float best = -INFINITY;
    int bi = 0;
    int g0 = c * CS;
    int g1 = min(g0 + CS, NG);
    const float* yr = y4p + (size_t)g0 * Y4STRIDE;
#pragma unroll 4
    for (int g = g0; g < g1; ++g, yr += Y4STRIDE) {
        v2f p0 = *(const v2f*)(yr + 0);
        v2f p1 = *(const v2f*)(yr + 2);
        v2f p2 = *(const v2f*)(yr + 4);
        v2f p3 = *(const v2f*)(yr + 6);
        float y8 = yr[11];
        v2f acc = a01 * p0;
        acc = __builtin_elementwise_fma(a23, p1, acc);
        acc = __builtin_elementwise_fma(a45, p2, acc);
        acc = __builtin_elementwise_fma(a67, p3, acc);
        float s = fmaf(a8, y8, acc.x + acc.y);
        if (s > best) { best = s; bi = g; }
    }
    pval[c * NB + b] = best;
    pidx[c * NB + b] = bi;
}

// ---------------- Kernel 3: combine pass-1 partials -> raw z vector per b ----------------
__global__ __launch_bounds__(256) void k_comb(const float* __restrict__ pval,
                                              const int* __restrict__ pidx,
                                              const float* __restrict__ y4p,
                                              float4* __restrict__ zbuf) {
    int b = blockIdx.x * 256 + threadIdx.x;
    float bv = -INFINITY; int zi = 0;
#pragma unroll
    for (int cc = 0; cc < NCHUNK; ++cc) {
        float v = pval[cc * NB + b];
        if (v > bv) { bv = v; zi = pidx[cc * NB + b]; }
    }
    const float* zr = y4p + (size_t)zi * Y4STRIDE;
    zbuf[b] = make_float4(zr[8], zr[9], zr[10], 0.0f);
}

// ---------------- Kernel 4: pass-2 masked partial argmax over a g-chunk ----------------
__global__ __launch_bounds__(256) void k_pass2(const float* __restrict__ f4,
                                               const float* __restrict__ y4p,
                                               const float4* __restrict__ zbuf,
                                               float* __restrict__ pval,
                                               int* __restrict__ pidx) {
    int b = blockIdx.x * 256 + threadIdx.x;
    int c = blockIdx.y;
    float4 zv = zbuf[b];
    v2f z01 = { zv.x, zv.y };
    float z2c = zv.z;
    const float* a = f4 + (size_t)b * 9;
    v2f a01 = { a[0], a[1] };
    v2f a23 = { a[2], a[3] };
    v2f a45 = { a[4], a[5] };
    v2f a67 = { a[6], a[7] };
    float a8 = a[8];
    float best = -INFINITY;
    int bi = 0;
    int g0 = c * CS;
    int g1 = min(g0 + CS, NG);
    const float* yr = y4p + (size_t)g0 * Y4STRIDE;
#pragma unroll 4
    for (int g = g0; g < g1; ++g, yr += Y4STRIDE) {
        v2f p0 = *(const v2f*)(yr + 0);
        v2f p1 = *(const v2f*)(yr + 2);
        v2f p2 = *(const v2f*)(yr + 4);
        v2f p3 = *(const v2f*)(yr + 6);
        v2f pv = *(const v2f*)(yr + 8);   // (vx, vy), 8B-aligned
        float vz = yr[10];
        float y8 = yr[11];
        v2f dacc = z01 * pv;
        float d = fmaf(z2c, vz, dacc.x + dacc.y);
        v2f acc = a01 * p0;
        acc = __builtin_elementwise_fma(a23, p1, acc);
        acc = __builtin_elementwise_fma(a45, p2, acc);
        acc = __builtin_elementwise_fma(a67, p3, acc);
        float s = fmaf(a8, y8, acc.x + acc.y);
        bool ok = (fabsf(d) < 0.2f) & (s > best);
        if (ok) { best = s; bi = g; }
    }
    pval[c * NB + b] = best;
    pidx[c * NB + b] = bi;
}

// ---------------- Kernel 5: finalize — frame, quaternion, boundary map ----------------
__global__ __launch_bounds__(256) void k_final(const float* __restrict__ f0,
                                               const float* __restrict__ y4p,
                                               const float4* __restrict__ zbuf,
                                               const float* __restrict__ p2val,
                                               const int* __restrict__ p2idx,
                                               float* __restrict__ out) {
    int b = blockIdx.x * 256 + threadIdx.x;
    float bx = -INFINITY; int xi = 0;
#pragma unroll
    for (int cc = 0; cc < NCHUNK; ++cc) {
        float v = p2val[cc * NB + b];
        if (v > bx) { bx = v; xi = p2idx[cc * NB + b]; }
    }
    float4 zv = zbuf[b];
    float zr0 = zv.x, zr1 = zv.y, zr2 = zv.z;
    const float* xr = y4p + (size_t)xi * Y4STRIDE;
    float xr0 = xr[8], xr1 = xr[9], xr2 = xr[10];
    // z = normalize(z_raw)
    float zn = sqrtf(zr0 * zr0 + zr1 * zr1 + zr2 * zr2);
    float zd = fmaxf(zn, 1e-12f);
    float z0 = zr0 / zd, z1 = zr1 / zd, z2 = zr2 / zd;
    // x = normalize(x_raw - (x_raw . z) z)
    float pr = xr0 * z0 + xr1 * z1 + xr2 * z2;
    float ux = xr0 - pr * z0, uy = xr1 - pr * z1, uz = xr2 - pr * z2;
    float xn = sqrtf(ux * ux + uy * uy + uz * uz);
    float xd = fmaxf(xn, 1e-12f);
    float x0 = ux / xd, x1 = uy / xd, x2 = uz / xd;
    // y = cross(z, x)
    float y0 = z1 * x2 - z2 * x1;
    float y1 = z2 * x0 - z0 * x2;
    float y2 = z0 * x1 - z1 * x0;
    // R columns = [x, y, z]
    float m00 = x0, m01 = y0, m02 = z0;
    float m10 = x1, m11 = y1, m12 = z1;
    float m20 = x2, m21 = y2, m22 = z2;
    float q0 = sqrtf(fmaxf(1.0f + m00 + m11 + m22, 0.0f));
    float q1 = sqrtf(fmaxf(1.0f + m00 - m11 - m22, 0.0f));
    float q2 = sqrtf(fmaxf(1.0f - m00 + m11 - m22, 0.0f));
    float q3 = sqrtf(fmaxf(1.0f - m00 - m11 + m22, 0.0f));
    int bq = 0; float qb = q0;
    if (q1 > qb) { qb = q1; bq = 1; }
    if (q2 > qb) { qb = q2; bq = 2; }
    if (q3 > qb) { qb = q3; bq = 3; }
    float dd = 2.0f * fmaxf(qb, 0.1f);
    float w, qx, qy, qz;
    if (bq == 0)      { w = q0 * q0;  qx = m21 - m12; qy = m02 - m20; qz = m10 - m01; }
    else if (bq == 1) { w = m21 - m12; qx = q1 * q1;  qy = m10 + m01; qz = m02 + m20; }
    else if (bq == 2) { w = m02 - m20; qx = m10 + m01; qy = q2 * q2;  qz = m12 + m21; }
    else              { w = m10 - m01; qx = m20 + m02; qy = m21 + m12; qz = q3 * q3; }
    out[b * 4 + 0] = w / dd;
    out[b * 4 + 1] = qx / dd;
    out[b * 4 + 2] = qy / dd;
    out[b * 4 + 3] = qz / dd;
    out[4 * NB + b] = f0[b] * (float)(180.0 / M_PI);
}

extern "C" void kernel_launch(void* const* d_in, const int* in_sizes, int n_in,
                              void* d_out, int out_size, void* d_ws, size_t ws_size,
                              hipStream_t stream) {
    const float* f0 = (const float*)d_in[0];   // [16384, 1]
    const float* f4 = (const float*)d_in[2];   // [16384, 9]
    const float* gv = (const float*)d_in[4];   // [10000, 3]
    float* out = (float*)d_out;                // q [16384,4] then boundary [16384]
    (void)in_sizes; (void)n_in; (void)out_size; (void)ws_size;

    // ws layout (floats): y4p (120000) | zbuf (NB*4) | Pval (NB*NCHUNK) | Pidx (NB*NCHUNK)
    // Pval/Pidx are written by pass1, consumed by k_comb, then REUSED by pass2 (safe:
    // kernel boundary orders the reuse). Total ~4.94 MB.
    float* Wf   = (float*)d_ws;
    float* y4p  = Wf;
    float4* zbuf = (float4*)(Wf + NG * Y4STRIDE);            // offset 480000 B, 16B aligned
    float* Pv   = Wf + NG * Y4STRIDE + NB * 4;
    int*   Pi   = (int*)(Wf + NG * Y4STRIDE + NB * 4 + NB * NCHUNK);

    k_y4<<<(NG + 255) / 256, 256, 0, stream>>>(gv, y4p);
    dim3 grid2(NB / 256, NCHUNK);
    k_pass1<<<grid2, 256, 0, stream>>>(f4, y4p, Pv, Pi);
    k_comb<<<NB / 256, 256, 0, stream>>>(Pv, Pi, y4p, zbuf);
    k_pass2<<<grid2, 256, 0, stream>>>(f4, y4p, zbuf, Pv, Pi);
    k_final<<<NB / 256, 256, 0, stream>>>(f0, y4p, zbuf, Pv, Pi, out);
}